// Round 6
// baseline (123.107 us; speedup 1.0000x reference)
//
#include <hip/hip_runtime.h>
#include <math.h>

#define NMAX 64
#define JITTER 1e-5

// Broadcast one lane's fp64 register to all lanes via v_readlane (SGPR pair).
// Lane index is a literal constant at every call site.
__device__ __forceinline__ double rdlane_f64(double x, int lane) {
    union { double d; int i[2]; } a, r;
    a.d = x;
    r.i[0] = __builtin_amdgcn_readlane(a.i[0], lane);
    r.i[1] = __builtin_amdgcn_readlane(a.i[1], lane);
    return r.d;
}

// ---------------- macro-generated straight-line register code ----------------
// R4 (#pragma unroll) and R5 (template constexpr indices) both left the
// per-lane arrays in scratch (VGPR_Count 148/144 << 280 needed; identical
// ~60us runtime). Named scalar locals bypass SROA entirely: mem2reg promotes
// every scalar alloca unconditionally. Macros emit c0..c63 / kx0..kx63 and
// the 64 fused steps as straight-line code with literal lane indices.

#define LOAD1(J) \
    double c##J  = (J == tid) ? cdiag : Klds[tid][J]; \
    double kx##J = (J == tid) ? kdiag : Klds[J][tid];

#define INNER1(K, J) \
    if constexpr (J > K) { \
        double ljk = rdlane_f64(c##K, J); \
        c##J  -= c##K * ljk; \
        kx##J -= ljk * vv; \
    }

#define INNERS(K) \
    INNER1(K, 0)  INNER1(K, 1)  INNER1(K, 2)  INNER1(K, 3) \
    INNER1(K, 4)  INNER1(K, 5)  INNER1(K, 6)  INNER1(K, 7) \
    INNER1(K, 8)  INNER1(K, 9)  INNER1(K, 10) INNER1(K, 11) \
    INNER1(K, 12) INNER1(K, 13) INNER1(K, 14) INNER1(K, 15) \
    INNER1(K, 16) INNER1(K, 17) INNER1(K, 18) INNER1(K, 19) \
    INNER1(K, 20) INNER1(K, 21) INNER1(K, 22) INNER1(K, 23) \
    INNER1(K, 24) INNER1(K, 25) INNER1(K, 26) INNER1(K, 27) \
    INNER1(K, 28) INNER1(K, 29) INNER1(K, 30) INNER1(K, 31) \
    INNER1(K, 32) INNER1(K, 33) INNER1(K, 34) INNER1(K, 35) \
    INNER1(K, 36) INNER1(K, 37) INNER1(K, 38) INNER1(K, 39) \
    INNER1(K, 40) INNER1(K, 41) INNER1(K, 42) INNER1(K, 43) \
    INNER1(K, 44) INNER1(K, 45) INNER1(K, 46) INNER1(K, 47) \
    INNER1(K, 48) INNER1(K, 49) INNER1(K, 50) INNER1(K, 51) \
    INNER1(K, 52) INNER1(K, 53) INNER1(K, 54) INNER1(K, 55) \
    INNER1(K, 56) INNER1(K, 57) INNER1(K, 58) INNER1(K, 59) \
    INNER1(K, 60) INNER1(K, 61) INNER1(K, 62) INNER1(K, 63)

// Fused step K: factor column K of Kn, immediately consume it for solve row K.
// The broadcast L[J][K] serves BOTH the trailing update and the forward solve.
#define STEP1(K) { \
    double dkk = rdlane_f64(c##K, K); \
    double inv = 1.0 / sqrt(dkk); \
    c##K *= inv; \
    double vv = kx##K * inv; \
    cum += vv * vv; \
    double var = os_ - cum; \
    double stdv = sqrt(var > 1e-12 ? var : 1e-12); \
    Klds[K][tid] = live ? stdv : 0.0; \
    INNERS(K) \
}

#define FOR64(M) \
    M(0)  M(1)  M(2)  M(3)  M(4)  M(5)  M(6)  M(7) \
    M(8)  M(9)  M(10) M(11) M(12) M(13) M(14) M(15) \
    M(16) M(17) M(18) M(19) M(20) M(21) M(22) M(23) \
    M(24) M(25) M(26) M(27) M(28) M(29) M(30) M(31) \
    M(32) M(33) M(34) M(35) M(36) M(37) M(38) M(39) \
    M(40) M(41) M(42) M(43) M(44) M(45) M(46) M(47) \
    M(48) M(49) M(50) M(51) M(52) M(53) M(54) M(55) \
    M(56) M(57) M(58) M(59) M(60) M(61) M(62) M(63)

// One 64-thread (single-wave) block per (batch, variable) pair.
// Lane i owns row i of C (Cholesky of Kn) and column i of Kxx (in-place solve)
// in 128 named fp64 scalars. Fixed 64 steps with identity padding == reference
// masked-point semantics. All math fp64 (mask output is hard 0/1).
__global__ __launch_bounds__(64, 1)
void gp_mask_kernel(const float* __restrict__ t,      // [B,L]
                    const int*   __restrict__ vid,    // [B,L]
                    const float* __restrict__ noise,  // [V]
                    const float* __restrict__ outscale,
                    const float* __restrict__ lscale,
                    const float* __restrict__ alpha,
                    const int*   __restrict__ pK,     // hyper_num_nodes
                    float* __restrict__ out_mask,     // [B,L,V*K]
                    float* __restrict__ out_gains,    // [B,L]
                    int B, int L, int V)
{
    const int b = blockIdx.x / V;
    const int v = blockIdx.x % V;
    const int tid = threadIdx.x;
    const int Knodes = pK[0];
    const int VK = V * Knodes;

    __shared__ double Klds[NMAX][NMAX + 1];  // Kxx staging; reused as std staging
    __shared__ double ts[NMAX];
    __shared__ float  tu[NMAX];
    __shared__ int    idx_u[NMAX];
    __shared__ int    oidx[NMAX];
    __shared__ int    cnt;

    // Zero this block's exclusively-owned mask slab: [b, :, v*K .. v*K+K)
    if ((Knodes & 3) == 0) {
        const int kq = Knodes >> 2;          // float4 chunks per row
        const float4 z = make_float4(0.f, 0.f, 0.f, 0.f);
        for (int q = tid; q < L * kq; q += 64) {
            int p = q / kq, g = q - p * kq;
            float4* dst = (float4*)(out_mask + ((size_t)b * L + p) * VK + v * Knodes) + g;
            *dst = z;
        }
    } else {
        for (int q = tid; q < L * Knodes; q += 64) {
            int p = q / Knodes, g = q - p * Knodes;
            out_mask[((size_t)b * L + p) * VK + v * Knodes + g] = 0.0f;
        }
    }

    if (tid == 0) cnt = 0;
    __syncthreads();

    // Collect this variable's points (order nondeterministic; sorted next).
    for (int i = tid; i < L; i += 64) {
        if (vid[b * L + i] == v) {
            int p = atomicAdd(&cnt, 1);
            if (p < NMAX) { idx_u[p] = i; tu[p] = t[b * L + i]; }
        }
    }
    __syncthreads();
    int n = __builtin_amdgcn_readfirstlane(cnt);
    if (n > NMAX) n = NMAX;

    // Stable rank sort by (t, original index) — matches jnp.argsort semantics.
    if (tid < n) {
        float tv = tu[tid]; int iv = idx_u[tid];
        int r = 0;
        for (int e = 0; e < n; e++) {
            float te = tu[e]; int ie = idx_u[e];
            if (te < tv || (te == tv && ie < iv)) r++;
        }
        ts[r] = (double)tv;
        oidx[r] = iv;
    }
    __syncthreads();

    const double os_ = (double)outscale[v];
    const double nz  = (double)noise[v];
    const double ls  = (double)lscale[v];
    const double al  = (double)alpha[v];
    const double isc = 1.0 / (2.0 * al * ls * ls);

    // Zero Kxx staging, then fill strict lower triangle (+ mirror) with RQ
    // values flattened across all 64 lanes (~n(n-1)/128 pow calls per lane).
    // Rows/cols >= n stay zero => identity-padded system (reference semantics).
    for (int q = tid; q < NMAX * (NMAX + 1); q += 64)
        ((double*)Klds)[q] = 0.0;
    __syncthreads();
    {
        const int P = n * (n - 1) / 2;
        for (int e = tid; e < P; e += 64) {
            int i = (int)((sqrt(8.0 * (double)e + 1.0) + 1.0) * 0.5);
            while (i * (i - 1) / 2 > e) --i;
            while ((i + 1) * i / 2 <= e) ++i;
            int j = e - i * (i - 1) / 2;
            double d = ts[i] - ts[j];
            double val = os_ * pow(1.0 + d * d * isc, -al);
            Klds[i][j] = val;
            Klds[j][i] = val;
        }
    }
    __syncthreads();

    const bool live = tid < n;
    const double cdiag = live ? (os_ + nz + JITTER) : 1.0;
    const double kdiag = live ? os_ : 0.0;

    // 128 named scalar registers: c<J> = Kn[tid][J], kx<J> = Kxx[J][tid].
    FOR64(LOAD1)
    __syncthreads();   // Klds re-purposed as std staging below

    // Fused right-looking Cholesky + forward solve, 64 straight-line steps.
    double cum = 0.0;
    FOR64(STEP1)
    __syncthreads();

    // sums[r] = row-sum of staged std; lane r owns sums[r].
    double s_mine = 0.0;
    for (int j = 0; j < NMAX; j++) s_mine += Klds[tid][j];

    // Gains + wave prefix-scan for cumulative gain, then group + scatter.
    if (n > 0) {
        double sprev = __shfl(s_mine, (tid == 0) ? 0 : tid - 1, 64);
        double prev  = (tid == 0) ? sqrt(os_) * (double)n : sprev;
        double g = 0.0;
        if (live) {
            g = prev - s_mine;
            if (g < 0.0) g = 0.0;
        }
        double sc = g;                                // inclusive prefix sum
        #pragma unroll
        for (int off = 1; off < 64; off <<= 1) {
            double o = __shfl_up(sc, off, 64);
            if (tid >= off) sc += o;
        }
        double total = __shfl(sc, n - 1, 64);
        if (live) {
            double denom = total > 1e-12 ? total : 1e-12;
            double frac = (sc - 0.5 * g) / denom;
            int grp = (int)floor(frac * (double)Knodes);
            if (grp < 0) grp = 0;
            if (grp > Knodes - 1) grp = Knodes - 1;
            int p = oidx[tid];
            out_mask[((size_t)b * L + p) * VK + v * Knodes + grp] = 1.0f;
            out_gains[(size_t)b * L + p] = (float)g;
        }
    }
}

extern "C" void kernel_launch(void* const* d_in, const int* in_sizes, int n_in,
                              void* d_out, int out_size, void* d_ws, size_t ws_size,
                              hipStream_t stream)
{
    const float* t     = (const float*)d_in[0];
    // d_in[1] = y: posterior variance is y-independent; unused.
    const int*   vid   = (const int*)d_in[2];
    const float* noise = (const float*)d_in[3];
    const float* osc   = (const float*)d_in[4];
    const float* ls    = (const float*)d_in[5];
    const float* al    = (const float*)d_in[6];
    const int*   pK    = (const int*)d_in[7];

    const int V = in_sizes[3];          // 16
    const int L = 512;                  // per reference setup
    const int B = in_sizes[0] / L;      // 8

    float* out_mask  = (float*)d_out;
    float* out_gains = (float*)d_out + ((size_t)out_size - (size_t)B * L);

    gp_mask_kernel<<<B * V, 64, 0, stream>>>(t, vid, noise, osc, ls, al, pK,
                                             out_mask, out_gains, B, L, V);
}